// Round 14
// baseline (163.344 us; speedup 1.0000x reference)
//
#include <hip/hip_runtime.h>

#define LDIM 4096
#define DDIM 64
#define KCODES 1024
#define BDIM 16
#define NROWS 65536   // BDIM * LDIM
#define NSLICE 8
#define SLICE_ROWS (NROWS / NSLICE)   // 8192

typedef __attribute__((ext_vector_type(8))) short short8;
typedef __attribute__((ext_vector_type(16))) float float16v;

__device__ __forceinline__ unsigned int orderf(float f) {
  unsigned int u = __float_as_uint(f);
  return (u & 0x80000000u) ? ~u : (u | 0x80000000u);
}

__device__ __forceinline__ unsigned long long shfl_xor_u64(unsigned long long v, int m) {
  int lo = __shfl_xor((int)(unsigned int)(v & 0xffffffffull), m, 64);
  int hi = __shfl_xor((int)(unsigned int)(v >> 32), m, 64);
  return ((unsigned long long)(unsigned int)hi << 32) | (unsigned int)lo;
}

// bf16 RNE high part (as ushort bits)
__device__ __forceinline__ unsigned int bf16_rne(float x) {
  unsigned int u = __float_as_uint(x);
  return (u + 0x7FFFu + ((u >> 16) & 1u)) >> 16;
}

// ---------------------------------------------------------------------------
// prep: per-code norm + softmax table + FRAGMENT-LOAD-ORDER bf16 codebook.
// ---------------------------------------------------------------------------
__global__ void prep_kernel(const float* __restrict__ Ew,
                            float* __restrict__ enorm,
                            float* __restrict__ SE,
                            unsigned short* __restrict__ Epk2) {
  int k = blockIdx.x;
  int d = threadIdx.x;
  float v = Ew[k * DDIM + d];
  float n2 = v * v;
  #pragma unroll
  for (int o = 32; o > 0; o >>= 1) n2 += __shfl_xor(n2, o, 64);
  float m = v;
  #pragma unroll
  for (int o = 32; o > 0; o >>= 1) m = fmaxf(m, __shfl_xor(m, o, 64));
  float e = __expf(v - m);
  float Z = e;
  #pragma unroll
  for (int o = 32; o > 0; o >>= 1) Z += __shfl_xor(Z, o, 64);
  SE[k * DDIM + d] = e / Z;
  if (d == 0) enorm[k] = n2;

  unsigned int rh = bf16_rne(v);
  float hif = __uint_as_float(rh << 16);
  unsigned int rl = bf16_rne(v - hif);
  int tile = k >> 5, mm = k & 31;
  int s = d >> 4, h = (d >> 3) & 1, j = d & 7;
  int base = tile * 4096 + (h * 32 + mm) * 8 + j;
  Epk2[base + s * 512]        = (unsigned short)rh;
  Epk2[base + (4 + s) * 512]  = (unsigned short)rl;
}

// ---------------------------------------------------------------------------
// argmin (R8 structure — best measured): LDS-free, barrier-free, atomic-free.
// ---------------------------------------------------------------------------
__launch_bounds__(256, 2)
__global__ void argmin_kernel(const float* __restrict__ inp,
                              const unsigned short* __restrict__ Epk2,
                              const float* __restrict__ enorm,
                              int* __restrict__ idx_ws,
                              float* __restrict__ outidx) {
  const int tid = threadIdx.x;
  const int lane = tid & 63;
  const int w = tid >> 6;
  const int half = lane >> 5;
  const int m = lane & 31;
  const int row_base = blockIdx.x * 128 + w * 32;
  const int b = row_base >> 12;
  const int l0 = row_base & 4095;
  const float* xp = inp + (size_t)b * DDIM * LDIM + l0 + m;

  short8 afr[8];
  #pragma unroll
  for (int s = 0; s < 4; s++) {
    #pragma unroll
    for (int j = 0; j < 8; j++) {
      int d = 16 * s + 8 * half + j;
      float x = xp[(size_t)d * LDIM];
      unsigned int rh = bf16_rne(x);
      float hif = __uint_as_float(rh << 16);
      unsigned int rl = bf16_rne(x - hif);
      afr[s][j] = (short)(unsigned short)rh;
      afr[4 + s][j] = (short)(unsigned short)rl;
    }
  }

  float bsc[16];
  int bix[16];
  #pragma unroll
  for (int j = 0; j < 16; j++) { bsc[j] = 1e30f; bix[j] = 0; }

  const unsigned short* eb = Epk2 + lane * 8;

  short8 bA[8], bB[8];
  float enA, enB;

  #pragma unroll
  for (int s = 0; s < 4; s++) {
    bA[s]     = *(const short8*)(eb + s * 512);
    bA[4 + s] = *(const short8*)(eb + 2048 + s * 512);
  }
  enA = enorm[m];

  #pragma unroll 1
  for (int i = 0; i < 16; i++) {
    const int tB = 2 * i + 1;
    {
      const unsigned short* p = eb + tB * 4096;
      #pragma unroll
      for (int s = 0; s < 4; s++) {
        bB[s]     = *(const short8*)(p + s * 512);
        bB[4 + s] = *(const short8*)(p + 2048 + s * 512);
      }
      enB = enorm[tB * 32 + m];
    }
    {
      float16v a0 = {}, a1 = {}, a2 = {};
      #pragma unroll
      for (int s = 0; s < 4; s++) {
        a0 = __builtin_amdgcn_mfma_f32_32x32x16_bf16(afr[s], bA[s], a0, 0, 0, 0);
        a1 = __builtin_amdgcn_mfma_f32_32x32x16_bf16(afr[s], bA[4 + s], a1, 0, 0, 0);
        a2 = __builtin_amdgcn_mfma_f32_32x32x16_bf16(afr[4 + s], bA[s], a2, 0, 0, 0);
      }
      int ci = 2 * i * 32 + m;
      #pragma unroll
      for (int j = 0; j < 16; j++) {
        float sc = fmaf(-2.f, a0[j] + a1[j] + a2[j], enA);
        if (sc < bsc[j]) { bsc[j] = sc; bix[j] = ci; }  // ascending ci: ties -> smaller
      }
    }
    if (i < 15) {
      const unsigned short* p = eb + (2 * i + 2) * 4096;
      #pragma unroll
      for (int s = 0; s < 4; s++) {
        bA[s]     = *(const short8*)(p + s * 512);
        bA[4 + s] = *(const short8*)(p + 2048 + s * 512);
      }
      enA = enorm[(2 * i + 2) * 32 + m];
    }
    {
      float16v a0 = {}, a1 = {}, a2 = {};
      #pragma unroll
      for (int s = 0; s < 4; s++) {
        a0 = __builtin_amdgcn_mfma_f32_32x32x16_bf16(afr[s], bB[s], a0, 0, 0, 0);
        a1 = __builtin_amdgcn_mfma_f32_32x32x16_bf16(afr[s], bB[4 + s], a1, 0, 0, 0);
        a2 = __builtin_amdgcn_mfma_f32_32x32x16_bf16(afr[4 + s], bB[s], a2, 0, 0, 0);
      }
      int ci = tB * 32 + m;
      #pragma unroll
      for (int j = 0; j < 16; j++) {
        float sc = fmaf(-2.f, a0[j] + a1[j] + a2[j], enB);
        if (sc < bsc[j]) { bsc[j] = sc; bix[j] = ci; }
      }
    }
  }

  #pragma unroll
  for (int j = 0; j < 16; j++) {
    unsigned long long key =
        ((unsigned long long)orderf(bsc[j]) << 32) | (unsigned int)bix[j];
    #pragma unroll
    for (int mm = 1; mm < 32; mm <<= 1) {
      unsigned long long o = shfl_xor_u64(key, mm);
      if (o < key) key = o;
    }
    if (m == 0) {
      int row_local = (j & 3) + 8 * (j >> 2) + 4 * half;
      int grow = row_base + row_local;
      int cidx = (int)(key & 0xffffffffull);
      idx_ws[grow] = cidx;
      outidx[grow] = (float)cidx;
    }
  }
}

// ---------------------------------------------------------------------------
// MERGED dw / out+KL dispatch. dw blocks FIRST.
// blocks [0,512): dw — MLP-restructured: ALL 8 x-float4 + 8 idx-int4 loads
//   issued upfront (16 independent 1 KB wave loads in flight, ONE latency
//   wait), then 32 LDS atomics from registers. No per-iteration dependency.
// blocks [512,768): out+KL, 256 rows x 64 d, LDS-transposed (R13 form).
// ---------------------------------------------------------------------------
__launch_bounds__(256)
__global__ void outkl_dw_kernel(const float* __restrict__ inp,
                                const float* __restrict__ Ew,
                                const float* __restrict__ SE,
                                const int* __restrict__ idx_ws,
                                float* __restrict__ out,
                                float* __restrict__ klacc,
                                float* __restrict__ partial,
                                float* __restrict__ pcounts) {
  __shared__ float smem[11528];   // 46.1 KB (out branch); dw uses first 8 KB
  const int tid = threadIdx.x;

  if (blockIdx.x < 512) {
    // ---------------- dw: dimension-sliced histogram, full MLP ----------
    float* dwp = smem;            // [1024]
    float* cnt = smem + KCODES;   // [1024]
    const int d = blockIdx.x & 63;
    const int slice = blockIdx.x >> 6;
    const bool do_cnt = (d == 0);
    const int r0 = slice * SLICE_ROWS;        // multiple of 8192
    const int b0 = r0 >> 12;                  // 2 batches per slice

    // issue ALL loads first: 8 x-float4 + 8 idx-int4, independent
    float4 xv[8];
    int4 iv[8];
    #pragma unroll
    for (int u = 0; u < 8; u++) {
      int s = u >> 2;              // sub-slice (batch)
      int it = u & 3;              // 1 KB chunk within 16 KB row
      int l = it * 1024 + tid * 4;
      xv[u] = *(const float4*)(inp + (size_t)(b0 + s) * DDIM * LDIM +
                               (size_t)d * LDIM + l);
      iv[u] = *(const int4*)(idx_ws + r0 + s * 4096 + l);
    }

    #pragma unroll
    for (int i = 0; i < KCODES / 256; i++) {
      dwp[tid + i * 256] = 0.f;
      cnt[tid + i * 256] = 0.f;
    }
    __syncthreads();

    #pragma unroll
    for (int u = 0; u < 8; u++) {
      atomicAdd(&dwp[iv[u].x], xv[u].x);
      atomicAdd(&dwp[iv[u].y], xv[u].y);
      atomicAdd(&dwp[iv[u].z], xv[u].z);
      atomicAdd(&dwp[iv[u].w], xv[u].w);
      if (do_cnt) {
        atomicAdd(&cnt[iv[u].x], 1.0f);
        atomicAdd(&cnt[iv[u].y], 1.0f);
        atomicAdd(&cnt[iv[u].z], 1.0f);
        atomicAdd(&cnt[iv[u].w], 1.0f);
      }
    }
    __syncthreads();

    float* dst = partial + ((size_t)slice * 64 + d) * KCODES;
    #pragma unroll
    for (int i = 0; i < KCODES / 256; i++) dst[tid + i * 256] = dwp[tid + i * 256];
    if (do_cnt) {
      float* cd = pcounts + (size_t)slice * KCODES;
      #pragma unroll
      for (int i = 0; i < KCODES / 256; i++) cd[tid + i * 256] = cnt[tid + i * 256];
    }
  } else {
    // ---------------- out + KL: 256 rows, LDS transpose (R13) -----------
    int*   kk  = (int*)smem;         // [256]
    float* Et  = smem + 256;         // [16][256]
    float* Qt  = smem + 4352;        // [16][256] (swizzled rows)
    float* Zp  = smem + 8448;        // [4][256]
    float* S1p = smem + 9472;        // [4][256]
    float* Up  = smem + 10496;       // [4][256]
    float* red4 = smem + 11520;      // [4]

    const int obid = blockIdx.x - 512;
    const int r0 = obid * 256;
    const int b = r0 >> 12;
    const int l0 = r0 & 4095;
    const float* xbase = inp + (size_t)b * DDIM * LDIM + l0;
    float* obase = out + (size_t)b * DDIM * LDIM + l0;
    const int w = tid >> 6, lane = tid & 63;

    kk[tid] = idx_ws[r0 + tid];
    __syncthreads();
    const int myk = kk[tid];
    const int gi = ((tid & 3) << 6) | (tid >> 2);

    float Zc[4] = {0.f, 0.f, 0.f, 0.f};
    float S1c[4] = {0.f, 0.f, 0.f, 0.f};
    float Uc[4] = {0.f, 0.f, 0.f, 0.f};

    #pragma unroll 1
    for (int c = 0; c < 4; c++) {
      {
        const float4* Ep = (const float4*)(Ew + myk * DDIM + c * 16);
        const float4* Qp = (const float4*)(SE + myk * DDIM + c * 16);
        #pragma unroll
        for (int q = 0; q < 4; q++) {
          float4 ev = Ep[q], qv = Qp[q];
          Et[(4 * q + 0) * 256 + tid] = ev.x;
          Et[(4 * q + 1) * 256 + tid] = ev.y;
          Et[(4 * q + 2) * 256 + tid] = ev.z;
          Et[(4 * q + 3) * 256 + tid] = ev.w;
          Qt[(4 * q + 0) * 256 + gi] = qv.x;
          Qt[(4 * q + 1) * 256 + gi] = qv.y;
          Qt[(4 * q + 2) * 256 + gi] = qv.z;
          Qt[(4 * q + 3) * 256 + gi] = qv.w;
        }
      }
      __syncthreads();
      #pragma unroll
      for (int t = 0; t < 4; t++) {
        const int dq = 4 * w + t;
        const int d = c * 16 + dq;
        float4 xv = *(const float4*)(xbase + (size_t)d * LDIM + lane * 4);
        float4 ov = *(const float4*)&Et[dq * 256 + lane * 4];
        *(float4*)(obase + (size_t)d * LDIM + lane * 4) = ov;
        #pragma unroll
        for (int j = 0; j < 4; j++) {
          float x = (j == 0) ? xv.x : (j == 1) ? xv.y : (j == 2) ? xv.z : xv.w;
          float e = __expf(x);
          Zc[j] += e;
          S1c[j] += e * x;
          Uc[j] += e * Qt[dq * 256 + (j << 6) + lane];
        }
      }
      __syncthreads();
    }

    #pragma unroll
    for (int j = 0; j < 4; j++) {
      Zp[w * 256 + 4 * lane + j] = Zc[j];
      S1p[w * 256 + 4 * lane + j] = S1c[j];
      Up[w * 256 + 4 * lane + j] = Uc[j];
    }
    __syncthreads();
    float Z = 0.f, S1 = 0.f, U = 0.f;
    #pragma unroll
    for (int w2 = 0; w2 < 4; w2++) {
      Z += Zp[w2 * 256 + tid];
      S1 += S1p[w2 * 256 + tid];
      U += Up[w2 * 256 + tid];
    }
    float kl = (S1 - U) / Z - __logf(Z);
    #pragma unroll
    for (int o = 32; o > 0; o >>= 1) kl += __shfl_xor(kl, o, 64);
    if (lane == 0) red4[w] = kl;
    __syncthreads();
    if (tid == 0)
      atomicAdd(klacc, red4[0] + red4[1] + red4[2] + red4[3]);
  }
}

// ---------------------------------------------------------------------------
// finalize: dw reduce + csp inline + embed epilogue; block 0 also computes
// perplexity and the loss scalar.
// ---------------------------------------------------------------------------
__launch_bounds__(256)
__global__ void finalize_kernel(const float* __restrict__ partial,
                                const float* __restrict__ pcounts,
                                const float* __restrict__ emaw,
                                const float* __restrict__ emacs,
                                const float* __restrict__ klacc,
                                float* __restrict__ emb_out,
                                float* __restrict__ loss_out,
                                float* __restrict__ perp_out) {
  __shared__ float red[4], red2[4];
  const int tid = threadIdx.x;
  const int i = blockIdx.x * 256 + tid;
  const int k = i >> 6, d = i & 63;

  float se = 0.f;
  #pragma unroll
  for (int t = 0; t < 4; t++) se += emacs[tid * 4 + t];
  #pragma unroll
  for (int o = 32; o > 0; o >>= 1) se += __shfl_xor(se, o, 64);
  if ((tid & 63) == 0) red[tid >> 6] = se;
  __syncthreads();
  const float S = red[0] + red[1] + red[2] + red[3];
  const float N = 0.9f * S + 0.1f * (float)NROWS;

  float c = 0.f;
  #pragma unroll
  for (int sl = 0; sl < NSLICE; sl++) c += pcounts[sl * KCODES + k];
  float cs = fmaf(0.1f, c, emacs[k] * 0.9f);
  float csp = (cs + 1e-5f) / (N + (float)KCODES * 1e-5f) * N;

  float s = 0.f;
  #pragma unroll
  for (int sl = 0; sl < NSLICE; sl++)
    s += partial[((size_t)sl * 64 + d) * KCODES + k];
  emb_out[i] = fmaf(0.1f, s, emaw[i] * 0.9f) / csp;

  if (blockIdx.x == 0) {
    float es = 0.f;
    #pragma unroll
    for (int t = 0; t < 4; t++) {
      int kk = tid * 4 + t;
      float cc = 0.f;
      #pragma unroll
      for (int sl = 0; sl < NSLICE; sl++) cc += pcounts[sl * KCODES + kk];
      float a = cc * (1.0f / (float)NROWS);
      es += a * logf(a + 1e-10f);
    }
    #pragma unroll
    for (int o = 32; o > 0; o >>= 1) es += __shfl_xor(es, o, 64);
    if ((tid & 63) == 0) red2[tid >> 6] = es;
    __syncthreads();
    if (tid == 0) {
      *perp_out = expf(-(red2[0] + red2[1] + red2[2] + red2[3]));
      *loss_out = 0.1f * (*klacc) * (1.0f / 16.0f);
    }
  }
}

extern "C" void kernel_launch(void* const* d_in, const int* in_sizes, int n_in,
                              void* d_out, int out_size, void* d_ws, size_t ws_size,
                              hipStream_t stream) {
  const float* inp   = (const float*)d_in[0];   // (16,64,4096)
  const float* Ew    = (const float*)d_in[1];   // (1024,64)
  const float* emacs = (const float*)d_in[2];   // (1024,)
  const float* emaw  = (const float*)d_in[3];   // (1024,64)

  float* out      = (float*)d_out;              // (16,64,4096) = 4194304
  float* loss_out = out + 4194304;
  float* perp_out = out + 4194305;
  float* emb_out  = out + 4194306;              // 65536
  float* idxf_out = out + 4194306 + 65536;      // 65536 (indices as float)

  char* ws = (char*)d_ws;
  int*   idx_ws  = (int*)(ws);                  // 262144 B
  float* klacc   = (float*)(ws + 262144);       // 256 B (zeroed)
  float* enorm   = (float*)(ws + 266496);       // 4096 B
  float* SE      = (float*)(ws + 274688);       // 262144 B -> ends 536832
  unsigned short* Epk2 = (unsigned short*)(ws + 536832);  // 262144 B
  // dw partials alias Epk2 (dead after argmin)
  float* partial = (float*)(ws + 536832);       // 2097152 B -> ends 2633984
  float* pcounts = (float*)(ws + 2633984);      // 32768 B  -> ends 2666752

  hipMemsetAsync(ws + 262144, 0, 256, stream);

  prep_kernel<<<KCODES, 64, 0, stream>>>(Ew, enorm, SE, Epk2);
  argmin_kernel<<<512, 256, 0, stream>>>(inp, Epk2, enorm, idx_ws, idxf_out);
  outkl_dw_kernel<<<768, 256, 0, stream>>>(inp, Ew, SE, idx_ws, out, klacc,
                                           partial, pcounts);
  finalize_kernel<<<NROWS / 256, 256, 0, stream>>>(partial, pcounts, emaw, emacs,
                                                   klacc, emb_out, loss_out,
                                                   perp_out);
}